// Round 15
// baseline (260.906 us; speedup 1.0000x reference)
//
#include <hip/hip_runtime.h>
#include <hip/hip_bf16.h>

// fp32 in / fp32 out. Internals: single-pass fp16 MFMA.
// Round 15: 256x256 gemm_qkv (8 waves, 128x64 wave tiles). Round-14 counters
// show gemm_qkv LDS-READ-bound (per K-step: 128KB LDS reads/CU vs ~320cyc
// MFMA/SIMD -> MfmaUtil 21.5%). LDS-bytes/MFMA ~ (m+n)/(m*n): 256^2 block
// with 128x64 wave tiles cuts LDS/MFMA by 25% and halves barriers/MFMA at
// UNCHANGED occupancy (1 blk x 8 waves = 2 waves/SIMD = today's 2x4).
// Sync structure = round-8-verified counted-vmcnt T4 (identical vmcnt(8)
// constants: still 8 gload_lds/thread/tile). attn/gemm2/pre_pass verbatim.
// Fusion remains abandoned (rounds 10/12). Error budget unchanged.
typedef _Float16 f16;
typedef _Float16 f16x4_t __attribute__((ext_vector_type(4)));
typedef _Float16 f16x8 __attribute__((ext_vector_type(8)));
typedef float f32x4 __attribute__((ext_vector_type(4)));

#define AS1(p) ((const __attribute__((address_space(1))) void*)(p))
#define AS3(p) ((__attribute__((address_space(3))) void*)(p))

__device__ __forceinline__ void gload_lds16(const f16* g, f16* l) {
    __builtin_amdgcn_global_load_lds(AS1(g), AS3(l), 16, 0, 0);
}

__device__ __forceinline__ f16x8 cvt8(float4 u, float4 v) {
    f16x8 r;
    r[0] = (f16)u.x; r[1] = (f16)u.y; r[2] = (f16)u.z; r[3] = (f16)u.w;
    r[4] = (f16)v.x; r[5] = (f16)v.y; r[6] = (f16)v.z; r[7] = (f16)v.w;
    return r;
}

// q pre-scale: 1/sqrt(64) * log2(e) so softmax is exp2(s)
#define Q_SCALE 0.180336880111f

// ---------------------------------------------------------------------------
// pre_pass: blocks 0..2047 grid-stride cvt x->x16, qkv_w->w16, out_w->ow16;
//           blocks 2048..2051 per-batch mask scan -> gpos (valid t list), nkv.
// ---------------------------------------------------------------------------
__global__ __launch_bounds__(256) void pre_pass(
    const float* __restrict__ x, const float* __restrict__ qw,
    const float* __restrict__ ow, const int* __restrict__ mask,
    f16* __restrict__ x16, f16* __restrict__ w16, f16* __restrict__ ow16,
    int* __restrict__ gpos, int* __restrict__ nkv)
{
    const int blk = blockIdx.x;
    if (blk >= 2048) {                 // scan: wave 0 of blocks 2048..2051
        const int b = blk - 2048;
        if (threadIdx.x < 64) {
            const int lane = threadIdx.x;
            const int* mb = mask + b * 2048;
            int run = 0;
            for (int c = 0; c < 2048; c += 64) {
                int v = (mb[c + lane] != 0) ? 1 : 0;
                unsigned long long bits = __ballot(v);
                int pre = __popcll(bits & ((1ull << lane) - 1ull));
                if (v) gpos[b * 2048 + run + pre] = c + lane;
                run += __popcll(bits);
            }
            if (lane == 0) nkv[b] = run;
        }
        return;
    }
    const int nx8 = 8192 * 1024 / 8;   // 1,048,576 groups of 8
    const int nw8 = 3072 * 1024 / 8;   //   393,216
    const int no8 = 1024 * 1024 / 8;   //   131,072
    int idx = blk * 256 + threadIdx.x;
    const int stride = 2048 * 256;
    for (int i = idx; i < nx8 + nw8 + no8; i += stride) {
        const float* s; f16* d;
        if (i < nx8)            { size_t o = (size_t)i * 8;                s = x  + o; d = x16  + o; }
        else if (i < nx8 + nw8) { size_t o = (size_t)(i - nx8) * 8;        s = qw + o; d = w16  + o; }
        else                    { size_t o = (size_t)(i - nx8 - nw8) * 8;  s = ow + o; d = ow16 + o; }
        float4 u = *(const float4*)s;
        float4 v = *(const float4*)(s + 4);
        *(f16x8*)d = cvt8(u, v);
    }
}

// ---------------------------------------------------------------------------
// gemm_qkv: 256x256 tiles, 512 threads (8 waves, wave tile 128x64), BK=64,
// double-buffered global_load_lds + counted-vmcnt loop (round-8 template,
// identical vmcnt constants). Grid 384: tiles 0..127 = Q (32m x 4n);
// 128..383 = KV (4 batches x 8mt x 8nt over compacted rows via gpos).
// LDS 128 KB -> 1 block/CU (8 waves = 2/SIMD, same occupancy as round 14).
// ---------------------------------------------------------------------------
__global__ __launch_bounds__(512) void gemm_qkv_f16(
    const f16* __restrict__ x16, const f16* __restrict__ w16,
    const float* __restrict__ bias, const int* __restrict__ gpos,
    const int* __restrict__ nkv, f16* __restrict__ q_g,
    f16* __restrict__ k_g, f16* __restrict__ vt_g)
{
    constexpr int BK = 64, K = 1024, NT = K / BK;
    __shared__ f16 As[2][256 * BK], Bs[2][256 * BK];   // 128 KB total

    const int tid  = threadIdx.x;
    const int lane = tid & 63, wave = tid >> 6;        // wave 0..7
    const int wr = wave >> 2, wc = wave & 3;           // wave tile (128x64)
    const int lrow = lane & 15, quad = lane >> 4;
    const int srow = lane >> 3;       // row within 8-row DMA group
    const int sgrp = lane & 7;        // LDS 16B-group
    const int x0 = ((quad)     ^ (lrow & 7)) * 8;
    const int x1 = ((4 + quad) ^ (lrow & 7)) * 8;

    const int tile = blockIdx.x;
    int b_kv = 0, mt = 0, nk = 0, nbase, n0;
    size_t m0 = 0;
    const int z = (tile >= 128);
    if (!z) {
        nbase = 0;
        m0 = (size_t)(tile >> 2) * 256;
        n0 = (tile & 3) * 256;
    } else {
        int t2 = tile - 128;
        b_kv = t2 >> 6;
        int rr = t2 & 63;
        mt = rr >> 3;
        n0 = (rr & 7) * 256;
        nk = nkv[b_kv];
        if (mt * 256 >= nk) return;
        nbase = 1024;
    }

    // per-thread staged-row base addrs, fixed across the whole K-loop.
    // 4 row-groups/thread per matrix: rg = wave*4+j in [0,32), row = rg*8+srow.
    const f16* arow[4];
    const f16* brow[4];
#pragma unroll
    for (int j = 0; j < 4; ++j) {
        int rit = (wave * 4 + j) * 8 + srow;     // row in tile [0,256)
        int trow;
        if (!z) {
            trow = (int)m0 + rit;                // global row [0,8192)
        } else {
            int ct = mt * 256 + rit;
            int t = (ct < nk) ? gpos[b_kv * 2048 + ct] : 0;  // tail -> t=0 (finite)
            trow = b_kv * 2048 + t;
        }
        arow[j] = x16 + (size_t)trow * K + (sgrp ^ srow) * 8;
        brow[j] = w16 + (size_t)(nbase + n0 + rit) * K + (sgrp ^ srow) * 8;
    }

    auto stage = [&](int k0, int bsel) {      // 8 loads/thread (4 A + 4 B)
#pragma unroll
        for (int j = 0; j < 4; ++j) {
            int rg = wave * 4 + j;
            gload_lds16(arow[j] + k0, &As[bsel][rg * 512 + lane * 8]);
            gload_lds16(brow[j] + k0, &Bs[bsel][rg * 512 + lane * 8]);
        }
    };

    f32x4 acc[8][4] = {};

    stage(0, 0);
    stage(BK, 1);
    asm volatile("s_waitcnt vmcnt(8)" ::: "memory");   // tile0 (oldest 8) done
    __builtin_amdgcn_s_barrier();                       // tile0 visible to all

    for (int kt = 0; kt < NT; ++kt) {
        const int cur = kt & 1;

        f16x8 b0[4], b1[4];
#pragma unroll
        for (int j = 0; j < 4; ++j) {
            const int r = (wc * 64 + j * 16 + lrow) * BK;
            b0[j] = *(const f16x8*)&Bs[cur][r + x0];
            b1[j] = *(const f16x8*)&Bs[cur][r + x1];
        }
        __builtin_amdgcn_s_setprio(1);
#pragma unroll
        for (int i = 0; i < 8; ++i) {
            const int r = (wr * 128 + i * 16 + lrow) * BK;
            f16x8 a0 = *(const f16x8*)&As[cur][r + x0];
            f16x8 a1 = *(const f16x8*)&As[cur][r + x1];
#pragma unroll
            for (int j = 0; j < 4; ++j) {
                acc[i][j] = __builtin_amdgcn_mfma_f32_16x16x32_f16(a0, b0[j], acc[i][j], 0, 0, 0);
                acc[i][j] = __builtin_amdgcn_mfma_f32_16x16x32_f16(a1, b1[j], acc[i][j], 0, 0, 0);
            }
        }
        __builtin_amdgcn_s_setprio(0);

        __builtin_amdgcn_s_barrier();       // #1: readers done (NO drain)
        if (kt + 2 < NT) {
            stage((kt + 2) * BK, cur);
            asm volatile("s_waitcnt vmcnt(8)" ::: "memory");  // own kt+1 done
        } else {
            asm volatile("s_waitcnt vmcnt(0)" ::: "memory");  // tail: drain
        }
        __builtin_amdgcn_s_barrier();       // #2: tile kt+1 visible to ALL
    }

    // epilogue: C/D layout col=lane&15, row=quad*4+reg
    if (!z) {
#pragma unroll
        for (int i = 0; i < 8; ++i) {
            size_t row = m0 + wr * 128 + i * 16 + quad * 4;
            int b = (int)(row >> 11);
            int t = (int)(row & 2047);
#pragma unroll
            for (int j = 0; j < 4; ++j) {
                int col = n0 + wc * 64 + j * 16 + lrow;       // [0,1024)
                float bb = bias[col];
                int hh = col >> 6, d = col & 63;
                size_t o = ((size_t)(b * 16 + hh) * 2048 + t) * 64 + d;
#pragma unroll
                for (int r = 0; r < 4; ++r)
                    q_g[o + (size_t)r * 64] = (f16)((acc[i][j][r] + bb) * Q_SCALE);
            }
        }
    } else {
        const int region = n0 >> 10;   // 0=k, 1=v (block-uniform; 1024%256==0)
#pragma unroll
        for (int i = 0; i < 8; ++i) {
            int ct = mt * 256 + wr * 128 + i * 16 + quad * 4;
#pragma unroll
            for (int j = 0; j < 4; ++j) {
                int col = n0 + wc * 64 + j * 16 + lrow;       // [0,2048)
                float bb = bias[1024 + col];
                int cl = col & 1023, hh = cl >> 6, d = cl & 63;
                size_t bh = (size_t)(b_kv * 16 + hh);
                if (region == 0) {
#pragma unroll
                    for (int r = 0; r < 4; ++r)
                        k_g[(bh * 2048 + ct + r) * 64 + d] = (f16)(acc[i][j][r] + bb);
                } else {
                    f16x4_t pv;
#pragma unroll
                    for (int r = 0; r < 4; ++r) pv[r] = (f16)(acc[i][j][r] + bb);
                    *(f16x4_t*)&vt_g[(bh * 64 + d) * 2048 + ct] = pv;
                }
            }
        }
    }
}

// ---------------------------------------------------------------------------
// GEMM2: out = att @ ow16^T + b. VERBATIM round 9/14 (counted-vmcnt, 128^2).
// ---------------------------------------------------------------------------
__global__ __launch_bounds__(256) void gemm2_f16(
    const f16* __restrict__ A16, const f16* __restrict__ Bw16,
    const float* __restrict__ bias, float* __restrict__ C,
    int M, int N, int K)
{
    constexpr int BK = 64;
    __shared__ f16 As[2][128 * BK], Bs[2][128 * BK];

    const int tid  = threadIdx.x;
    const int lane = tid & 63, wave = tid >> 6;
    const int wy = wave >> 1, wx = wave & 1;
    const int lrow = lane & 15, quad = lane >> 4;
    const size_t m0 = (size_t)blockIdx.y * 128;
    const size_t n0 = (size_t)blockIdx.x * 128;
    const int srow = lane >> 3, sgrp = lane & 7;
    const int x0 = ((quad)     ^ (lrow & 7)) * 8;
    const int x1 = ((4 + quad) ^ (lrow & 7)) * 8;

    const f16* arow[4];
    const f16* brow[4];
#pragma unroll
    for (int j = 0; j < 4; ++j) {
        int rit = (wave * 4 + j) * 8 + srow;
        arow[j] = A16  + (m0 + rit) * (size_t)K + (sgrp ^ srow) * 8;
        brow[j] = Bw16 + (n0 + rit) * (size_t)K + (sgrp ^ srow) * 8;
    }

    auto stage = [&](int k0, int bsel) {      // 8 loads/thread
#pragma unroll
        for (int j = 0; j < 4; ++j) {
            int rg = wave * 4 + j;
            gload_lds16(arow[j] + k0, &As[bsel][rg * 512 + lane * 8]);
            gload_lds16(brow[j] + k0, &Bs[bsel][rg * 512 + lane * 8]);
        }
    };

    f32x4 acc[4][4] = {};
    const int NT = K / BK;

    stage(0, 0);
    stage(BK, 1);
    asm volatile("s_waitcnt vmcnt(8)" ::: "memory");
    __builtin_amdgcn_s_barrier();

    for (int kt = 0; kt < NT; ++kt) {
        const int cur = kt & 1;

        f16x8 a0[4], a1[4], b0[4], b1[4];
#pragma unroll
        for (int i = 0; i < 4; ++i) {
            const int r = (wy * 64 + i * 16 + lrow) * BK;
            a0[i] = *(const f16x8*)&As[cur][r + x0];
            a1[i] = *(const f16x8*)&As[cur][r + x1];
        }
#pragma unroll
        for (int j = 0; j < 4; ++j) {
            const int r = (wx * 64 + j * 16 + lrow) * BK;
            b0[j] = *(const f16x8*)&Bs[cur][r + x0];
            b1[j] = *(const f16x8*)&Bs[cur][r + x1];
        }
        __builtin_amdgcn_s_setprio(1);
#pragma unroll
        for (int i = 0; i < 4; ++i)
#pragma unroll
            for (int j = 0; j < 4; ++j) {
                acc[i][j] = __builtin_amdgcn_mfma_f32_16x16x32_f16(a0[i], b0[j], acc[i][j], 0, 0, 0);
                acc[i][j] = __builtin_amdgcn_mfma_f32_16x16x32_f16(a1[i], b1[j], acc[i][j], 0, 0, 0);
            }
        __builtin_amdgcn_s_setprio(0);

        __builtin_amdgcn_s_barrier();       // #1: readers done (NO drain)
        if (kt + 2 < NT) {
            stage((kt + 2) * BK, cur);
            asm volatile("s_waitcnt vmcnt(8)" ::: "memory");
        } else {
            asm volatile("s_waitcnt vmcnt(0)" ::: "memory");
        }
        __builtin_amdgcn_s_barrier();       // #2: tile kt+1 visible
    }

#pragma unroll
    for (int i = 0; i < 4; ++i) {
        size_t row = m0 + wy * 64 + i * 16 + quad * 4;
#pragma unroll
        for (int j = 0; j < 4; ++j) {
            size_t col = n0 + wx * 64 + j * 16 + lrow;
            float bb = bias[col];
#pragma unroll
            for (int r = 0; r < 4; ++r)
                C[(row + r) * N + col] = acc[i][j][r] + bb;
        }
    }
}

// ---------------------------------------------------------------------------
// Attention over COMPACTED keys; counted-vmcnt loop (VERBATIM round 9/14,
// passing). Pt is wave-private. Tail keys gated by rem.
// ---------------------------------------------------------------------------
__global__ __launch_bounds__(256) void attn_f16(
    const f16* __restrict__ q_g, const f16* __restrict__ k_g,
    const f16* __restrict__ vt_g, const int* __restrict__ nkv,
    f16* __restrict__ att, int B, int T)
{
    constexpr int LDP = 72;
    __shared__ f16 Ks_s[2][64 * 64];
    __shared__ f16 Vt_s[2][64 * 64];
    __shared__ f16 Pt[128 * LDP];

    const int tid  = threadIdx.x;
    const int lane = tid & 63, wave = tid >> 6;
    const int lrow = lane & 15, quad = lane >> 4;
    const int bid = ((int)blockIdx.x & 7) * 128 + ((int)blockIdx.x >> 3);
    const int qt = bid & 15;
    const int h  = (bid >> 4) & 15;
    const int b  = bid >> 8;
    const size_t base = (size_t)b * T;
    const size_t bh = (size_t)(b * 16 + h);
    const f16* qg_base = q_g  + bh * (2048 * 64);
    const f16* kg_base = k_g  + bh * (2048 * 64);
    const f16* vt_base = vt_g + bh * (64 * 2048);

    const int nk = nkv[b];
    const int ntiles = (nk + 63) >> 6;

    const int x0 = ((quad)     ^ (lrow & 7)) * 8;
    const int x1 = ((4 + quad) ^ (lrow & 7)) * 8;

    f16x8 aq[2][2];
#pragma unroll
    for (int qi = 0; qi < 2; ++qi)
#pragma unroll
        for (int ks = 0; ks < 2; ++ks)
            aq[qi][ks] = *(const f16x8*)&qg_base[
                (size_t)(qt * 128 + wave * 32 + qi * 16 + lrow) * 64 + ks * 32 + quad * 8];

    f32x4 oacc[2][4] = {};
    float l_part[2] = {0.f, 0.f};

    const int srow0 = (lane >> 3);
    const int sgrp  = (lane & 7);

    auto stage = [&](int kt, int bsel) {      // 4 loads/thread
        const f16* kT = kg_base + kt * 4096;
#pragma unroll
        for (int j = 0; j < 2; ++j) {
            int rg  = wave + j * 4;
            int row = rg * 8 + srow0;
            int grp = sgrp ^ (row & 7);
            gload_lds16(&kT[row * 64 + grp * 8], &Ks_s[bsel][rg * 512 + lane * 8]);
            gload_lds16(&vt_base[(size_t)row * 2048 + kt * 64 + grp * 8],
                        &Vt_s[bsel][rg * 512 + lane * 8]);
        }
    };

    stage(0, 0);
    stage(1, 1);                               // in-bounds even if ntiles==1
    asm volatile("s_waitcnt vmcnt(4)" ::: "memory");   // tile0 done
    __builtin_amdgcn_s_barrier();                       // tile0 visible

    for (int kt = 0; kt < ntiles; ++kt) {
        const int cur = kt & 1;
        const f16* Ks = Ks_s[cur];
        const f16* Vt = Vt_s[cur];

        f32x4 s[2][4];
        __builtin_amdgcn_s_setprio(1);
#pragma unroll
        for (int ni = 0; ni < 4; ++ni) {
            const int key = ni * 16 + lrow;
            f16x8 k0 = *(const f16x8*)&Ks[key * 64 + x0];
            f16x8 k1 = *(const f16x8*)&Ks[key * 64 + x1];
#pragma unroll
            for (int qi = 0; qi < 2; ++qi) {
                f32x4 t = {0.f, 0.f, 0.f, 0.f};
                t = __builtin_amdgcn_mfma_f32_16x16x32_f16(k0, aq[qi][0], t, 0, 0, 0);
                t = __builtin_amdgcn_mfma_f32_16x16x32_f16(k1, aq[qi][1], t, 0, 0, 0);
                s[qi][ni] = t;
            }
        }
        __builtin_amdgcn_s_setprio(0);

        const int rem = nk - kt * 64;
        auto softmax = [&](bool masked) {
#pragma unroll
            for (int qi = 0; qi < 2; ++qi)
#pragma unroll
                for (int ni = 0; ni < 4; ++ni) {
                    float p[4];
#pragma unroll
                    for (int r = 0; r < 4; ++r) {
                        float e = __builtin_amdgcn_exp2f(s[qi][ni][r]);
                        p[r] = (!masked || (ni * 16 + quad * 4 + r) < rem) ? e : 0.f;
                    }
                    l_part[qi] += (p[0] + p[1]) + (p[2] + p[3]);
                    f16x4_t pk;
#pragma unroll
                    for (int r = 0; r < 4; ++r) pk[r] = (f16)p[r];
                    *(f16x4_t*)&Pt[(wave * 32 + qi * 16 + lrow) * LDP + ni * 16 + quad * 4] = pk;
                }
        };
        if (rem >= 64) softmax(false); else softmax(true);

        f16x8 pf[2][2];
#pragma unroll
        for (int qi = 0; qi < 2; ++qi)
#pragma unroll
            for (int ks = 0; ks < 2; ++ks)
                pf[qi][ks] = *(const f16x8*)&Pt[(wave * 32 + qi * 16 + lrow) * LDP + ks * 32 + quad * 8];
        __builtin_amdgcn_s_setprio(1);
#pragma unroll
        for (int di = 0; di < 4; ++di) {
            const int d = di * 16 + lrow;
            f16x8 v0 = *(const f16x8*)&Vt[d * 64 + x0];
            f16x8 v1 = *(const f16x8*)&Vt[d * 64 + x1];
#pragma unroll
            for (int qi = 0; qi < 2; ++qi) {
                oacc[qi][di] = __builtin_amdgcn_mfma_f32_16x16x32_f16(v0, pf[qi][0], oacc[qi][di], 0, 0, 0);
                oacc[qi][di] = __builtin_amdgcn_mfma_f32_16x16x32_f16(v1, pf[qi][1], oacc[qi][di], 0, 0, 0);
            }
        }
        __builtin_amdgcn_s_setprio(0);

        __builtin_amdgcn_s_barrier();       // #1: readers done (NO drain)
        if (kt + 2 < ntiles) {
            stage(kt + 2, cur);
            asm volatile("s_waitcnt vmcnt(4)" ::: "memory");  // own kt+1 done
        } else {
            asm volatile("s_waitcnt vmcnt(0)" ::: "memory");  // tail: drain
        }
        __builtin_amdgcn_s_barrier();       // #2: tile kt+1 visible
    }

#pragma unroll
    for (int qi = 0; qi < 2; ++qi) {
        float v = l_part[qi];
        v += __shfl_xor(v, 16);
        v += __shfl_xor(v, 32);
        float inv = 1.f / v;
        int q = qt * 128 + wave * 32 + qi * 16 + lrow;
#pragma unroll
        for (int di = 0; di < 4; ++di) {
            f16x4_t o;
#pragma unroll
            for (int r = 0; r < 4; ++r) o[r] = (f16)(oacc[qi][di][r] * inv);
            *(f16x4_t*)&att[(base + q) * 1024 + h * 64 + di * 16 + quad * 4] = o;
        }
    }
}

// ---------------------------------------------------------------------------
extern "C" void kernel_launch(void* const* d_in, const int* in_sizes, int n_in,
                              void* d_out, int out_size, void* d_ws, size_t ws_size,
                              hipStream_t stream) {
    const float* x     = (const float*)d_in[0];   // [4,2048,1024]
    const int*   mask  = (const int*)d_in[1];     // [4,1,1,2048]
    const float* qkv_w = (const float*)d_in[2];   // [3072,1024]
    const float* qkv_b = (const float*)d_in[3];   // [3072]
    const float* out_w = (const float*)d_in[4];   // [1024,1024]
    const float* out_b = (const float*)d_in[5];   // [1024]
    float* out = (float*)d_out;                   // [4,2048,1024] fp32

    const int B = 4, T = 2048;
    const int M = B * T;                          // 8192
    char* ws = (char*)d_ws;
    f16* q_g = (f16*)(ws);                        // 16.78 MB [b,h,t,d] (pre-scaled)
    f16* k_g = (f16*)(ws + 16777216);             // 16.78 MB [b,h,ct,d] compacted
    f16* vt  = (f16*)(ws + 33554432);             // 16.78 MB [b,h,d,ct] compacted
    f16* att = (f16*)(ws + 50331648);             // 16.78 MB [t][1024]

    // d_out scratch (33.5 MB): x16 | w16 | ow16 | gpos | nkv. All written in
    // pre_pass (strictly before their readers' dispatches); all dead before
    // gemm2 writes out.
    f16* x16  = (f16*)d_out;                      // 16.78 MB
    f16* w16  = (f16*)((char*)d_out + 16777216);  //  6.29 MB
    f16* ow16 = (f16*)((char*)d_out + 23068672);  //  2.10 MB
    int* gpos = (int*)((char*)d_out + 25165824);  // 32 KB
    int* nkv  = gpos + 4 * 2048;                  // 16 B

    dim3 blk(256);
    pre_pass<<<dim3(2052), blk, 0, stream>>>(x, qkv_w, out_w, mask, x16, w16, ow16, gpos, nkv);
    gemm_qkv_f16<<<dim3(384), dim3(512), 0, stream>>>(x16, w16, qkv_b, gpos, nkv, q_g, k_g, vt);
    attn_f16<<<dim3(B * 16 * 16), blk, 0, stream>>>(q_g, k_g, vt, nkv, att, B, T);
    gemm2_f16<<<dim3(1024 / 128, M / 128), blk, 0, stream>>>(att, ow16, out_b, out, M, 1024, 1024);
}

// Round 16
// 249.998 us; speedup vs baseline: 1.0436x; 1.0436x over previous
//
#include <hip/hip_runtime.h>
#include <hip/hip_bf16.h>

// fp32 in / fp32 out. Internals: single-pass fp16 MFMA.
// Round 16: REVERT to round 14 (best verified, 251.1us). Round 15's 256^2
// gemm_qkv regressed (65.3->75.8us): 128KB LDS -> 1 block/CU killed the
// co-resident-block overlap AND 384 tiles / 256 CUs left a half-empty
// second dispatch round. The wave-tile economics were right (FETCH 81->64MB)
// but capturing them needs the full 8-phase 256^2 schedule (HK m201) -- a
// new sync template, out of budget after two structure regressions.
// Structural note: gemm_qkv runs at ~85% of measured ds_read_b128 ceiling
// (m134: 85 B/cyc/CU) for the 64x64-wave-tile / 2-block structure; MfmaUtil
// ~21.5% is that structure's LDS-read-throughput bound.
// Stack: f16 MFMA + key compaction (mask kills ~half the keys) + compact-
// before-GEMM gather + counted-vmcnt T4 loops + XOR-involution LDS (0 bank
// conflicts) + XCD swizzle (attn) + 4 launches. Error: absmax 2e-3 (thr 8e-3).
typedef _Float16 f16;
typedef _Float16 f16x4_t __attribute__((ext_vector_type(4)));
typedef _Float16 f16x8 __attribute__((ext_vector_type(8)));
typedef float f32x4 __attribute__((ext_vector_type(4)));

#define AS1(p) ((const __attribute__((address_space(1))) void*)(p))
#define AS3(p) ((__attribute__((address_space(3))) void*)(p))

__device__ __forceinline__ void gload_lds16(const f16* g, f16* l) {
    __builtin_amdgcn_global_load_lds(AS1(g), AS3(l), 16, 0, 0);
}

__device__ __forceinline__ f16x8 cvt8(float4 u, float4 v) {
    f16x8 r;
    r[0] = (f16)u.x; r[1] = (f16)u.y; r[2] = (f16)u.z; r[3] = (f16)u.w;
    r[4] = (f16)v.x; r[5] = (f16)v.y; r[6] = (f16)v.z; r[7] = (f16)v.w;
    return r;
}

// q pre-scale: 1/sqrt(64) * log2(e) so softmax is exp2(s)
#define Q_SCALE 0.180336880111f

// ---------------------------------------------------------------------------
// pre_pass: blocks 0..2047 grid-stride cvt x->x16, qkv_w->w16, out_w->ow16;
//           blocks 2048..2051 per-batch mask scan -> gpos (valid t list), nkv.
// ---------------------------------------------------------------------------
__global__ __launch_bounds__(256) void pre_pass(
    const float* __restrict__ x, const float* __restrict__ qw,
    const float* __restrict__ ow, const int* __restrict__ mask,
    f16* __restrict__ x16, f16* __restrict__ w16, f16* __restrict__ ow16,
    int* __restrict__ gpos, int* __restrict__ nkv)
{
    const int blk = blockIdx.x;
    if (blk >= 2048) {                 // scan: wave 0 of blocks 2048..2051
        const int b = blk - 2048;
        if (threadIdx.x < 64) {
            const int lane = threadIdx.x;
            const int* mb = mask + b * 2048;
            int run = 0;
            for (int c = 0; c < 2048; c += 64) {
                int v = (mb[c + lane] != 0) ? 1 : 0;
                unsigned long long bits = __ballot(v);
                int pre = __popcll(bits & ((1ull << lane) - 1ull));
                if (v) gpos[b * 2048 + run + pre] = c + lane;
                run += __popcll(bits);
            }
            if (lane == 0) nkv[b] = run;
        }
        return;
    }
    const int nx8 = 8192 * 1024 / 8;   // 1,048,576 groups of 8
    const int nw8 = 3072 * 1024 / 8;   //   393,216
    const int no8 = 1024 * 1024 / 8;   //   131,072
    int idx = blk * 256 + threadIdx.x;
    const int stride = 2048 * 256;
    for (int i = idx; i < nx8 + nw8 + no8; i += stride) {
        const float* s; f16* d;
        if (i < nx8)            { size_t o = (size_t)i * 8;                s = x  + o; d = x16  + o; }
        else if (i < nx8 + nw8) { size_t o = (size_t)(i - nx8) * 8;        s = qw + o; d = w16  + o; }
        else                    { size_t o = (size_t)(i - nx8 - nw8) * 8;  s = ow + o; d = ow16 + o; }
        float4 u = *(const float4*)s;
        float4 v = *(const float4*)(s + 4);
        *(f16x8*)d = cvt8(u, v);
    }
}

// ---------------------------------------------------------------------------
// gemm_qkv: VERBATIM round 8/9/14 (passing). grid (24,64). bx<8: Q all rows.
// bx>=8: K/V over COMPACTED rows (gathered via gpos). Counted-vmcnt loop.
// ---------------------------------------------------------------------------
__global__ __launch_bounds__(256) void gemm_qkv_f16(
    const f16* __restrict__ x16, const f16* __restrict__ w16,
    const float* __restrict__ bias, const int* __restrict__ gpos,
    const int* __restrict__ nkv, f16* __restrict__ q_g,
    f16* __restrict__ k_g, f16* __restrict__ vt_g)
{
    constexpr int BK = 64, K = 1024, NT = K / BK;
    __shared__ f16 As[2][128 * BK], Bs[2][128 * BK];   // 64 KB total

    const int tid  = threadIdx.x;
    const int lane = tid & 63, wave = tid >> 6;
    const int wy = wave >> 1, wx = wave & 1;
    const int lrow = lane & 15, quad = lane >> 4;
    const int srow = lane >> 3;       // row within 8-row DMA group
    const int sgrp = lane & 7;        // LDS 16B-group
    const int x0 = ((quad)     ^ (lrow & 7)) * 8;
    const int x1 = ((4 + quad) ^ (lrow & 7)) * 8;

    const int bx = blockIdx.x, by = blockIdx.y;
    const int z = (bx >= 8);
    int b_kv = 0, mt = 0, nk = 0, nbase, n0;
    if (!z) {
        nbase = 0; n0 = bx * 128;
    } else {
        b_kv = by >> 4; mt = by & 15;
        nk = nkv[b_kv];
        if (mt * 128 >= nk) return;
        nbase = 1024; n0 = (bx - 8) * 128;
    }

    const f16* arow[4];
    const f16* brow[4];
#pragma unroll
    for (int j = 0; j < 4; ++j) {
        int rit = (wave * 4 + j) * 8 + srow;     // row in tile [0,128)
        int trow;
        if (!z) {
            trow = by * 128 + rit;               // global row [0,8192)
        } else {
            int ct = mt * 128 + rit;
            int t = (ct < nk) ? gpos[b_kv * 2048 + ct] : 0;  // tail -> t=0 (finite)
            trow = b_kv * 2048 + t;
        }
        arow[j] = x16 + (size_t)trow * K + (sgrp ^ srow) * 8;
        brow[j] = w16 + (size_t)(nbase + n0 + rit) * K + (sgrp ^ srow) * 8;
    }

    auto stage = [&](int k0, int bsel) {      // 8 loads/thread
#pragma unroll
        for (int j = 0; j < 4; ++j) {
            int rg = wave * 4 + j;
            gload_lds16(arow[j] + k0, &As[bsel][rg * 512 + lane * 8]);
            gload_lds16(brow[j] + k0, &Bs[bsel][rg * 512 + lane * 8]);
        }
    };

    f32x4 acc[4][4] = {};

    stage(0, 0);
    stage(BK, 1);
    asm volatile("s_waitcnt vmcnt(8)" ::: "memory");   // tile0 (oldest 8) done
    __builtin_amdgcn_s_barrier();                       // tile0 visible to all

    for (int kt = 0; kt < NT; ++kt) {
        const int cur = kt & 1;

        f16x8 a0[4], a1[4], b0[4], b1[4];
#pragma unroll
        for (int i = 0; i < 4; ++i) {
            const int r = (wy * 64 + i * 16 + lrow) * BK;
            a0[i] = *(const f16x8*)&As[cur][r + x0];
            a1[i] = *(const f16x8*)&As[cur][r + x1];
        }
#pragma unroll
        for (int j = 0; j < 4; ++j) {
            const int r = (wx * 64 + j * 16 + lrow) * BK;
            b0[j] = *(const f16x8*)&Bs[cur][r + x0];
            b1[j] = *(const f16x8*)&Bs[cur][r + x1];
        }
        __builtin_amdgcn_s_setprio(1);
#pragma unroll
        for (int i = 0; i < 4; ++i)
#pragma unroll
            for (int j = 0; j < 4; ++j) {
                acc[i][j] = __builtin_amdgcn_mfma_f32_16x16x32_f16(a0[i], b0[j], acc[i][j], 0, 0, 0);
                acc[i][j] = __builtin_amdgcn_mfma_f32_16x16x32_f16(a1[i], b1[j], acc[i][j], 0, 0, 0);
            }
        __builtin_amdgcn_s_setprio(0);

        __builtin_amdgcn_s_barrier();       // #1: readers done (NO drain)
        if (kt + 2 < NT) {
            stage((kt + 2) * BK, cur);
            asm volatile("s_waitcnt vmcnt(8)" ::: "memory");  // own kt+1 done
        } else {
            asm volatile("s_waitcnt vmcnt(0)" ::: "memory");  // tail: drain
        }
        __builtin_amdgcn_s_barrier();       // #2: tile kt+1 visible to ALL
    }

    if (!z) {
#pragma unroll
        for (int i = 0; i < 4; ++i) {
            size_t row = (size_t)by * 128 + wy * 64 + i * 16 + quad * 4;
            int b = (int)(row >> 11);
            int t = (int)(row & 2047);
#pragma unroll
            for (int j = 0; j < 4; ++j) {
                int col = n0 + wx * 64 + j * 16 + lrow;
                float bb = bias[col];
                int hh = col >> 6, d = col & 63;
                size_t o = ((size_t)(b * 16 + hh) * 2048 + t) * 64 + d;
#pragma unroll
                for (int r = 0; r < 4; ++r)
                    q_g[o + (size_t)r * 64] = (f16)((acc[i][j][r] + bb) * Q_SCALE);
            }
        }
    } else {
        const int region = n0 >> 10;   // 0=k, 1=v (block-uniform)
#pragma unroll
        for (int i = 0; i < 4; ++i) {
            int ct = mt * 128 + wy * 64 + i * 16 + quad * 4;
#pragma unroll
            for (int j = 0; j < 4; ++j) {
                int col = n0 + wx * 64 + j * 16 + lrow;       // [0,2048)
                float bb = bias[1024 + col];
                int cl = col & 1023, hh = cl >> 6, d = cl & 63;
                size_t bh = (size_t)(b_kv * 16 + hh);
                if (region == 0) {
#pragma unroll
                    for (int r = 0; r < 4; ++r)
                        k_g[(bh * 2048 + ct + r) * 64 + d] = (f16)(acc[i][j][r] + bb);
                } else {
                    f16x4_t pv;
#pragma unroll
                    for (int r = 0; r < 4; ++r) pv[r] = (f16)(acc[i][j][r] + bb);
                    *(f16x4_t*)&vt_g[(bh * 64 + d) * 2048 + ct] = pv;
                }
            }
        }
    }
}

// ---------------------------------------------------------------------------
// GEMM2: out = att @ ow16^T + b. VERBATIM round 9/14 (counted-vmcnt, 128^2).
// ---------------------------------------------------------------------------
__global__ __launch_bounds__(256) void gemm2_f16(
    const f16* __restrict__ A16, const f16* __restrict__ Bw16,
    const float* __restrict__ bias, float* __restrict__ C,
    int M, int N, int K)
{
    constexpr int BK = 64;
    __shared__ f16 As[2][128 * BK], Bs[2][128 * BK];

    const int tid  = threadIdx.x;
    const int lane = tid & 63, wave = tid >> 6;
    const int wy = wave >> 1, wx = wave & 1;
    const int lrow = lane & 15, quad = lane >> 4;
    const size_t m0 = (size_t)blockIdx.y * 128;
    const size_t n0 = (size_t)blockIdx.x * 128;
    const int srow = lane >> 3, sgrp = lane & 7;
    const int x0 = ((quad)     ^ (lrow & 7)) * 8;
    const int x1 = ((4 + quad) ^ (lrow & 7)) * 8;

    const f16* arow[4];
    const f16* brow[4];
#pragma unroll
    for (int j = 0; j < 4; ++j) {
        int rit = (wave * 4 + j) * 8 + srow;
        arow[j] = A16  + (m0 + rit) * (size_t)K + (sgrp ^ srow) * 8;
        brow[j] = Bw16 + (n0 + rit) * (size_t)K + (sgrp ^ srow) * 8;
    }

    auto stage = [&](int k0, int bsel) {      // 8 loads/thread
#pragma unroll
        for (int j = 0; j < 4; ++j) {
            int rg = wave * 4 + j;
            gload_lds16(arow[j] + k0, &As[bsel][rg * 512 + lane * 8]);
            gload_lds16(brow[j] + k0, &Bs[bsel][rg * 512 + lane * 8]);
        }
    };

    f32x4 acc[4][4] = {};
    const int NT = K / BK;

    stage(0, 0);
    stage(BK, 1);
    asm volatile("s_waitcnt vmcnt(8)" ::: "memory");
    __builtin_amdgcn_s_barrier();

    for (int kt = 0; kt < NT; ++kt) {
        const int cur = kt & 1;

        f16x8 a0[4], a1[4], b0[4], b1[4];
#pragma unroll
        for (int i = 0; i < 4; ++i) {
            const int r = (wy * 64 + i * 16 + lrow) * BK;
            a0[i] = *(const f16x8*)&As[cur][r + x0];
            a1[i] = *(const f16x8*)&As[cur][r + x1];
        }
#pragma unroll
        for (int j = 0; j < 4; ++j) {
            const int r = (wx * 64 + j * 16 + lrow) * BK;
            b0[j] = *(const f16x8*)&Bs[cur][r + x0];
            b1[j] = *(const f16x8*)&Bs[cur][r + x1];
        }
        __builtin_amdgcn_s_setprio(1);
#pragma unroll
        for (int i = 0; i < 4; ++i)
#pragma unroll
            for (int j = 0; j < 4; ++j) {
                acc[i][j] = __builtin_amdgcn_mfma_f32_16x16x32_f16(a0[i], b0[j], acc[i][j], 0, 0, 0);
                acc[i][j] = __builtin_amdgcn_mfma_f32_16x16x32_f16(a1[i], b1[j], acc[i][j], 0, 0, 0);
            }
        __builtin_amdgcn_s_setprio(0);

        __builtin_amdgcn_s_barrier();       // #1: readers done (NO drain)
        if (kt + 2 < NT) {
            stage((kt + 2) * BK, cur);
            asm volatile("s_waitcnt vmcnt(8)" ::: "memory");
        } else {
            asm volatile("s_waitcnt vmcnt(0)" ::: "memory");
        }
        __builtin_amdgcn_s_barrier();       // #2: tile kt+1 visible
    }

#pragma unroll
    for (int i = 0; i < 4; ++i) {
        size_t row = m0 + wy * 64 + i * 16 + quad * 4;
#pragma unroll
        for (int j = 0; j < 4; ++j) {
            size_t col = n0 + wx * 64 + j * 16 + lrow;
            float bb = bias[col];
#pragma unroll
            for (int r = 0; r < 4; ++r)
                C[(row + r) * N + col] = acc[i][j][r] + bb;
        }
    }
}

// ---------------------------------------------------------------------------
// Attention over COMPACTED keys; counted-vmcnt loop (VERBATIM round 9/14,
// passing). Pt is wave-private. Tail keys gated by rem.
// ---------------------------------------------------------------------------
__global__ __launch_bounds__(256) void attn_f16(
    const f16* __restrict__ q_g, const f16* __restrict__ k_g,
    const f16* __restrict__ vt_g, const int* __restrict__ nkv,
    f16* __restrict__ att, int B, int T)
{
    constexpr int LDP = 72;
    __shared__ f16 Ks_s[2][64 * 64];
    __shared__ f16 Vt_s[2][64 * 64];
    __shared__ f16 Pt[128 * LDP];

    const int tid  = threadIdx.x;
    const int lane = tid & 63, wave = tid >> 6;
    const int lrow = lane & 15, quad = lane >> 4;
    const int bid = ((int)blockIdx.x & 7) * 128 + ((int)blockIdx.x >> 3);
    const int qt = bid & 15;
    const int h  = (bid >> 4) & 15;
    const int b  = bid >> 8;
    const size_t base = (size_t)b * T;
    const size_t bh = (size_t)(b * 16 + h);
    const f16* qg_base = q_g  + bh * (2048 * 64);
    const f16* kg_base = k_g  + bh * (2048 * 64);
    const f16* vt_base = vt_g + bh * (64 * 2048);

    const int nk = nkv[b];
    const int ntiles = (nk + 63) >> 6;

    const int x0 = ((quad)     ^ (lrow & 7)) * 8;
    const int x1 = ((4 + quad) ^ (lrow & 7)) * 8;

    f16x8 aq[2][2];
#pragma unroll
    for (int qi = 0; qi < 2; ++qi)
#pragma unroll
        for (int ks = 0; ks < 2; ++ks)
            aq[qi][ks] = *(const f16x8*)&qg_base[
                (size_t)(qt * 128 + wave * 32 + qi * 16 + lrow) * 64 + ks * 32 + quad * 8];

    f32x4 oacc[2][4] = {};
    float l_part[2] = {0.f, 0.f};

    const int srow0 = (lane >> 3);
    const int sgrp  = (lane & 7);

    auto stage = [&](int kt, int bsel) {      // 4 loads/thread
        const f16* kT = kg_base + kt * 4096;
#pragma unroll
        for (int j = 0; j < 2; ++j) {
            int rg  = wave + j * 4;
            int row = rg * 8 + srow0;
            int grp = sgrp ^ (row & 7);
            gload_lds16(&kT[row * 64 + grp * 8], &Ks_s[bsel][rg * 512 + lane * 8]);
            gload_lds16(&vt_base[(size_t)row * 2048 + kt * 64 + grp * 8],
                        &Vt_s[bsel][rg * 512 + lane * 8]);
        }
    };

    stage(0, 0);
    stage(1, 1);                               // in-bounds even if ntiles==1
    asm volatile("s_waitcnt vmcnt(4)" ::: "memory");   // tile0 done
    __builtin_amdgcn_s_barrier();                       // tile0 visible

    for (int kt = 0; kt < ntiles; ++kt) {
        const int cur = kt & 1;
        const f16* Ks = Ks_s[cur];
        const f16* Vt = Vt_s[cur];

        f32x4 s[2][4];
        __builtin_amdgcn_s_setprio(1);
#pragma unroll
        for (int ni = 0; ni < 4; ++ni) {
            const int key = ni * 16 + lrow;
            f16x8 k0 = *(const f16x8*)&Ks[key * 64 + x0];
            f16x8 k1 = *(const f16x8*)&Ks[key * 64 + x1];
#pragma unroll
            for (int qi = 0; qi < 2; ++qi) {
                f32x4 t = {0.f, 0.f, 0.f, 0.f};
                t = __builtin_amdgcn_mfma_f32_16x16x32_f16(k0, aq[qi][0], t, 0, 0, 0);
                t = __builtin_amdgcn_mfma_f32_16x16x32_f16(k1, aq[qi][1], t, 0, 0, 0);
                s[qi][ni] = t;
            }
        }
        __builtin_amdgcn_s_setprio(0);

        const int rem = nk - kt * 64;
        auto softmax = [&](bool masked) {
#pragma unroll
            for (int qi = 0; qi < 2; ++qi)
#pragma unroll
                for (int ni = 0; ni < 4; ++ni) {
                    float p[4];
#pragma unroll
                    for (int r = 0; r < 4; ++r) {
                        float e = __builtin_amdgcn_exp2f(s[qi][ni][r]);
                        p[r] = (!masked || (ni * 16 + quad * 4 + r) < rem) ? e : 0.f;
                    }
                    l_part[qi] += (p[0] + p[1]) + (p[2] + p[3]);
                    f16x4_t pk;
#pragma unroll
                    for (int r = 0; r < 4; ++r) pk[r] = (f16)p[r];
                    *(f16x4_t*)&Pt[(wave * 32 + qi * 16 + lrow) * LDP + ni * 16 + quad * 4] = pk;
                }
        };
        if (rem >= 64) softmax(false); else softmax(true);

        f16x8 pf[2][2];
#pragma unroll
        for (int qi = 0; qi < 2; ++qi)
#pragma unroll
            for (int ks = 0; ks < 2; ++ks)
                pf[qi][ks] = *(const f16x8*)&Pt[(wave * 32 + qi * 16 + lrow) * LDP + ks * 32 + quad * 8];
        __builtin_amdgcn_s_setprio(1);
#pragma unroll
        for (int di = 0; di < 4; ++di) {
            const int d = di * 16 + lrow;
            f16x8 v0 = *(const f16x8*)&Vt[d * 64 + x0];
            f16x8 v1 = *(const f16x8*)&Vt[d * 64 + x1];
#pragma unroll
            for (int qi = 0; qi < 2; ++qi) {
                oacc[qi][di] = __builtin_amdgcn_mfma_f32_16x16x32_f16(v0, pf[qi][0], oacc[qi][di], 0, 0, 0);
                oacc[qi][di] = __builtin_amdgcn_mfma_f32_16x16x32_f16(v1, pf[qi][1], oacc[qi][di], 0, 0, 0);
            }
        }
        __builtin_amdgcn_s_setprio(0);

        __builtin_amdgcn_s_barrier();       // #1: readers done (NO drain)
        if (kt + 2 < ntiles) {
            stage(kt + 2, cur);
            asm volatile("s_waitcnt vmcnt(4)" ::: "memory");  // own kt+1 done
        } else {
            asm volatile("s_waitcnt vmcnt(0)" ::: "memory");  // tail: drain
        }
        __builtin_amdgcn_s_barrier();       // #2: tile kt+1 visible
    }

#pragma unroll
    for (int qi = 0; qi < 2; ++qi) {
        float v = l_part[qi];
        v += __shfl_xor(v, 16);
        v += __shfl_xor(v, 32);
        float inv = 1.f / v;
        int q = qt * 128 + wave * 32 + qi * 16 + lrow;
#pragma unroll
        for (int di = 0; di < 4; ++di) {
            f16x4_t o;
#pragma unroll
            for (int r = 0; r < 4; ++r) o[r] = (f16)(oacc[qi][di][r] * inv);
            *(f16x4_t*)&att[(base + q) * 1024 + h * 64 + di * 16 + quad * 4] = o;
        }
    }
}

// ---------------------------------------------------------------------------
extern "C" void kernel_launch(void* const* d_in, const int* in_sizes, int n_in,
                              void* d_out, int out_size, void* d_ws, size_t ws_size,
                              hipStream_t stream) {
    const float* x     = (const float*)d_in[0];   // [4,2048,1024]
    const int*   mask  = (const int*)d_in[1];     // [4,1,1,2048]
    const float* qkv_w = (const float*)d_in[2];   // [3072,1024]
    const float* qkv_b = (const float*)d_in[3];   // [3072]
    const float* out_w = (const float*)d_in[4];   // [1024,1024]
    const float* out_b = (const float*)d_in[5];   // [1024]
    float* out = (float*)d_out;                   // [4,2048,1024] fp32

    const int B = 4, T = 2048;
    const int M = B * T;                          // 8192
    char* ws = (char*)d_ws;
    f16* q_g = (f16*)(ws);                        // 16.78 MB [b,h,t,d] (pre-scaled)
    f16* k_g = (f16*)(ws + 16777216);             // 16.78 MB [b,h,ct,d] compacted
    f16* vt  = (f16*)(ws + 33554432);             // 16.78 MB [b,h,d,ct] compacted
    f16* att = (f16*)(ws + 50331648);             // 16.78 MB [t][1024]

    // d_out scratch (33.5 MB): x16 | w16 | ow16 | gpos | nkv. All written in
    // pre_pass (strictly before their readers' dispatches); all dead before
    // gemm2 writes out.
    f16* x16  = (f16*)d_out;                      // 16.78 MB
    f16* w16  = (f16*)((char*)d_out + 16777216);  //  6.29 MB
    f16* ow16 = (f16*)((char*)d_out + 23068672);  //  2.10 MB
    int* gpos = (int*)((char*)d_out + 25165824);  // 32 KB
    int* nkv  = gpos + 4 * 2048;                  // 16 B

    dim3 blk(256);
    pre_pass<<<dim3(2052), blk, 0, stream>>>(x, qkv_w, out_w, mask, x16, w16, ow16, gpos, nkv);
    gemm_qkv_f16<<<dim3(24, 64), blk, 0, stream>>>(x16, w16, qkv_b, gpos, nkv, q_g, k_g, vt);
    attn_f16<<<dim3(B * 16 * 16), blk, 0, stream>>>(q_g, k_g, vt, nkv, att, B, T);
    gemm2_f16<<<dim3(1024 / 128, M / 128), blk, 0, stream>>>(att, ow16, out_b, out, M, 1024, 1024);
}